// Round 1
// baseline (652.678 us; speedup 1.0000x reference)
//
#include <hip/hip_runtime.h>

#define IN_FEAT 256
#define OUT_FEAT 128

// ---------------- GEMM: support = X @ W ----------------
// X [M,256] row-major, W [256,128] row-major, S [M,128]
// Block: 256 threads, tile BM=64 x BN=128, BK=32.
// Thread micro-tile: 8 rows x 4 cols. tx = t&31 -> cols tx*4..tx*4+3, ty = t>>5 -> rows ty*8..ty*8+7.
__global__ __launch_bounds__(256) void gcn_gemm_kernel(const float* __restrict__ X,
                                                       const float* __restrict__ W,
                                                       float* __restrict__ S, int M)
{
    __shared__ float Xs[64][33];    // +1 pad: rows differ by 1 bank
    __shared__ float Ws[32][128];

    const int t  = threadIdx.x;
    const int m0 = blockIdx.x * 64;
    const int tx = t & 31;
    const int ty = t >> 5;

    float acc[8][4];
#pragma unroll
    for (int i = 0; i < 8; ++i)
#pragma unroll
        for (int j = 0; j < 4; ++j) acc[i][j] = 0.f;

    for (int k0 = 0; k0 < IN_FEAT; k0 += 32) {
        // Load X tile: 64x32 = 2048 floats, 8 per thread, coalesced (lane -> consecutive k)
#pragma unroll
        for (int i = 0; i < 8; ++i) {
            int idx = t + i * 256;
            int r = idx >> 5, c = idx & 31;
            int gr = m0 + r;
            Xs[r][c] = (gr < M) ? X[(size_t)gr * IN_FEAT + k0 + c] : 0.f;
        }
        // Load W tile: 32x128 = 4096 floats, 16 per thread, coalesced
#pragma unroll
        for (int i = 0; i < 16; ++i) {
            int idx = t + i * 256;
            int r = idx >> 7, c = idx & 127;
            Ws[r][c] = W[(size_t)(k0 + r) * OUT_FEAT + c];
        }
        __syncthreads();

#pragma unroll
        for (int kk = 0; kk < 32; ++kk) {
            float4 w4 = *reinterpret_cast<const float4*>(&Ws[kk][tx * 4]);
#pragma unroll
            for (int i = 0; i < 8; ++i) {
                float x = Xs[ty * 8 + i][kk];
                acc[i][0] += x * w4.x;
                acc[i][1] += x * w4.y;
                acc[i][2] += x * w4.z;
                acc[i][3] += x * w4.w;
            }
        }
        __syncthreads();
    }

#pragma unroll
    for (int i = 0; i < 8; ++i) {
        int gr = m0 + ty * 8 + i;
        if (gr < M) {
            *reinterpret_cast<float4*>(&S[(size_t)gr * OUT_FEAT + tx * 4]) =
                make_float4(acc[i][0], acc[i][1], acc[i][2], acc[i][3]);
        }
    }
}

// ---------------- SpMM: out[r] = sum_e vals[e] * support[cols[e]] for rows[e]==r ----------------
// rows sorted ascending. One block (128 threads) per output row; thread f owns feature f.
__global__ __launch_bounds__(128) void gcn_spmm_kernel(const int* __restrict__ rows,
                                                       const int* __restrict__ cols,
                                                       const float* __restrict__ vals,
                                                       const float* __restrict__ support,
                                                       float* __restrict__ out,
                                                       int n_edges)
{
    const int r = blockIdx.x;
    const int f = threadIdx.x;

    __shared__ int   s_range[2];
    __shared__ int   s_col[128];
    __shared__ float s_val[128];

    if (f < 2) {
        // lower_bound for r (f==0) and r+1 (f==1)
        int key = r + f;
        int lo = 0, hi = n_edges;
        while (lo < hi) {
            int mid = (lo + hi) >> 1;
            if (rows[mid] < key) lo = mid + 1;
            else hi = mid;
        }
        s_range[f] = lo;
    }
    __syncthreads();
    const int start = s_range[0];
    const int end   = s_range[1];

    float acc = 0.f;
    for (int base = start; base < end; base += 128) {
        int nb = end - base;
        if (nb > 128) nb = 128;
        __syncthreads();
        if (f < nb) {
            s_col[f] = cols[base + f];
            s_val[f] = vals[base + f];
        }
        __syncthreads();
        for (int i = 0; i < nb; ++i) {
            acc += s_val[i] * support[(size_t)s_col[i] * OUT_FEAT + f];
        }
    }
    out[(size_t)r * OUT_FEAT + f] = acc;
}

extern "C" void kernel_launch(void* const* d_in, const int* in_sizes, int n_in,
                              void* d_out, int out_size, void* d_ws, size_t ws_size,
                              hipStream_t stream) {
    const float* X    = (const float*)d_in[0];
    const float* W    = (const float*)d_in[1];
    const int*   rows = (const int*)d_in[2];
    const int*   cols = (const int*)d_in[3];
    const float* vals = (const float*)d_in[4];
    float*       out  = (float*)d_out;

    const int M = in_sizes[0] / IN_FEAT;   // 100000
    const int E = in_sizes[2];             // 3200000

    float* support = (float*)d_ws;         // M * 128 floats = 51.2 MB

    gcn_gemm_kernel<<<(M + 63) / 64, 256, 0, stream>>>(X, W, support, M);
    gcn_spmm_kernel<<<M, 128, 0, stream>>>(rows, cols, vals, support, out, E);
}

// Round 2
// 328.096 us; speedup vs baseline: 1.9893x; 1.9893x over previous
//
#include <hip/hip_runtime.h>

#define IN_FEAT 256
#define OUT_FEAT 128

typedef __attribute__((ext_vector_type(8))) short bf16x8;
typedef __attribute__((ext_vector_type(4))) float f32x4;

static __device__ __forceinline__ unsigned short f2bf(float f) {
    union { float f; unsigned u; } v; v.f = f;
    unsigned u = v.u;
    return (unsigned short)((u + 0x7FFFu + ((u >> 16) & 1u)) >> 16);
}
static __device__ __forceinline__ float bfl(unsigned u) {
    union { unsigned u; float f; } x; x.u = u << 16; return x.f;
}
static __device__ __forceinline__ float bfh(unsigned u) {
    union { unsigned u; float f; } x; x.u = u & 0xFFFF0000u; return x.f;
}

// ---- prep: Wt[n][k] = bf16(W[k][n]), Wt is [128][256] bf16 ----
__global__ __launch_bounds__(256) void prep_wt(const float* __restrict__ W,
                                               unsigned short* __restrict__ Wt) {
    int idx = blockIdx.x * 256 + threadIdx.x;      // 0..32767
    int n = idx >> 8, k = idx & 255;
    Wt[idx] = f2bf(W[(size_t)k * OUT_FEAT + n]);
}

// ---- prep: row_ptr[i] = lower_bound(rows, i), i in [0, N] ----
__global__ __launch_bounds__(256) void rowptr_kernel(const int* __restrict__ rows,
                                                     int* __restrict__ row_ptr,
                                                     int E, int N) {
    int i = blockIdx.x * 256 + threadIdx.x;
    if (i > N) return;
    int lo = 0, hi = E;
    while (lo < hi) {
        int mid = (lo + hi) >> 1;
        if (rows[mid] < i) lo = mid + 1; else hi = mid;
    }
    row_ptr[i] = lo;
}

// ---- GEMM: S_bf16 = bf16( X @ W )  via MFMA 16x16x32 bf16 ----
// BM=128, BN=128 (full), BK=64. 256 threads = 4 waves, wave (wm,wn) owns 64x64.
// LDS tiles [128 rows][64 k] bf16 with slot swizzle s' = s ^ (r&7)  (slot = 16B = 8 bf16).
__global__ __launch_bounds__(256) void gemm_bf16(const float* __restrict__ X,
                                                 const unsigned short* __restrict__ Wt,
                                                 unsigned short* __restrict__ S, int M) {
    __shared__ unsigned short As[128 * 64];
    __shared__ unsigned short Bs[128 * 64];

    const int t = threadIdx.x;
    const int m0 = blockIdx.x * 128;
    const int lane = t & 63;
    const int w = t >> 6;
    const int wm = w >> 1, wn = w & 1;
    const int lr = lane & 15, lg = lane >> 4;

    f32x4 acc[4][4];
#pragma unroll
    for (int mi = 0; mi < 4; ++mi)
#pragma unroll
        for (int ni = 0; ni < 4; ++ni)
            acc[mi][ni] = (f32x4){0.f, 0.f, 0.f, 0.f};

    const int r_st = t >> 1;        // staged row 0..127
    const int h_st = t & 1;         // k half (32 floats each)

    for (int k0 = 0; k0 < IN_FEAT; k0 += 64) {
        // stage A: X[m0..m0+128][k0..k0+64] fp32 -> bf16 swizzled LDS
        int gr = m0 + r_st; if (gr >= M) gr = M - 1;
        const float4* xp = (const float4*)(X + (size_t)gr * IN_FEAT + k0 + h_st * 32);
#pragma unroll
        for (int j = 0; j < 4; ++j) {
            float4 f0 = xp[2 * j], f1 = xp[2 * j + 1];
            uint4 pk;
            pk.x = (unsigned)f2bf(f0.x) | ((unsigned)f2bf(f0.y) << 16);
            pk.y = (unsigned)f2bf(f0.z) | ((unsigned)f2bf(f0.w) << 16);
            pk.z = (unsigned)f2bf(f1.x) | ((unsigned)f2bf(f1.y) << 16);
            pk.w = (unsigned)f2bf(f1.z) | ((unsigned)f2bf(f1.w) << 16);
            int s = h_st * 4 + j;
            *(uint4*)((char*)As + r_st * 128 + ((s ^ (r_st & 7)) << 4)) = pk;
        }
        // stage B: Wt[n][k0..k0+64] bf16 -> swizzled LDS (already bf16)
        const uint4* wp = (const uint4*)(Wt + (size_t)r_st * 256 + k0 + h_st * 32);
#pragma unroll
        for (int j = 0; j < 4; ++j) {
            uint4 pk = wp[j];
            int s = h_st * 4 + j;
            *(uint4*)((char*)Bs + r_st * 128 + ((s ^ (r_st & 7)) << 4)) = pk;
        }
        __syncthreads();

#pragma unroll
        for (int kb = 0; kb < 2; ++kb) {
            const int sb = kb * 4 + lg;          // slot index 0..7
            bf16x8 a[4], b[4];
#pragma unroll
            for (int mi = 0; mi < 4; ++mi) {
                int r = wm * 64 + mi * 16 + lr;
                a[mi] = *(const bf16x8*)((const char*)As + r * 128 + ((sb ^ (r & 7)) << 4));
            }
#pragma unroll
            for (int ni = 0; ni < 4; ++ni) {
                int r = wn * 64 + ni * 16 + lr;
                b[ni] = *(const bf16x8*)((const char*)Bs + r * 128 + ((sb ^ (r & 7)) << 4));
            }
#pragma unroll
            for (int mi = 0; mi < 4; ++mi)
#pragma unroll
                for (int ni = 0; ni < 4; ++ni)
                    acc[mi][ni] = __builtin_amdgcn_mfma_f32_16x16x32_bf16(a[mi], b[ni], acc[mi][ni], 0, 0, 0);
        }
        __syncthreads();
    }

    // epilogue: D[row=(lane>>4)*4+reg][col=lane&15]
#pragma unroll
    for (int mi = 0; mi < 4; ++mi) {
#pragma unroll
        for (int j = 0; j < 4; ++j) {
            int row = m0 + wm * 64 + mi * 16 + lg * 4 + j;
            if (row < M) {
#pragma unroll
                for (int ni = 0; ni < 4; ++ni) {
                    int col = wn * 64 + ni * 16 + lr;
                    S[(size_t)row * OUT_FEAT + col] = f2bf(acc[mi][ni][j]);
                }
            }
        }
    }
}

// ---- SpMM: out[r] = sum_e vals[e] * S[cols[e]]  (S bf16 [N][128]) ----
// 256 threads = 4 waves, one wave per row. lane: g=lane>>4 edge subgroup, fb=lane&15 feat block.
__global__ __launch_bounds__(256) void spmm_bf16(const int* __restrict__ cols,
                                                 const float* __restrict__ vals,
                                                 const unsigned short* __restrict__ S,
                                                 const int* __restrict__ row_ptr,
                                                 float* __restrict__ out, int N) {
    const int w = threadIdx.x >> 6;
    const int lane = threadIdx.x & 63;
    const int r = blockIdx.x * 4 + w;
    if (r >= N) return;
    const int g = lane >> 4;
    const int fb = lane & 15;
    const int start = row_ptr[r], end = row_ptr[r + 1];

    float acc[8] = {0.f, 0.f, 0.f, 0.f, 0.f, 0.f, 0.f, 0.f};
    const unsigned short* Sb = S + fb * 8;

    for (int base = start; base < end; base += 8) {
        int e0 = base + g;
        int e1 = base + 4 + g;
        if (e0 < end) {
            int c = cols[e0]; float v = vals[e0];
            uint4 p = *(const uint4*)(Sb + (size_t)c * OUT_FEAT);
            acc[0] += v * bfl(p.x); acc[1] += v * bfh(p.x);
            acc[2] += v * bfl(p.y); acc[3] += v * bfh(p.y);
            acc[4] += v * bfl(p.z); acc[5] += v * bfh(p.z);
            acc[6] += v * bfl(p.w); acc[7] += v * bfh(p.w);
        }
        if (e1 < end) {
            int c = cols[e1]; float v = vals[e1];
            uint4 p = *(const uint4*)(Sb + (size_t)c * OUT_FEAT);
            acc[0] += v * bfl(p.x); acc[1] += v * bfh(p.x);
            acc[2] += v * bfl(p.y); acc[3] += v * bfh(p.y);
            acc[4] += v * bfl(p.z); acc[5] += v * bfh(p.z);
            acc[6] += v * bfl(p.w); acc[7] += v * bfh(p.w);
        }
    }

#pragma unroll
    for (int j = 0; j < 8; ++j) {
        acc[j] += __shfl_xor(acc[j], 16);
        acc[j] += __shfl_xor(acc[j], 32);
    }
    if (g == 0) {
        float4 o0 = make_float4(acc[0], acc[1], acc[2], acc[3]);
        float4 o1 = make_float4(acc[4], acc[5], acc[6], acc[7]);
        *(float4*)(out + (size_t)r * OUT_FEAT + fb * 8) = o0;
        *(float4*)(out + (size_t)r * OUT_FEAT + fb * 8 + 4) = o1;
    }
}

extern "C" void kernel_launch(void* const* d_in, const int* in_sizes, int n_in,
                              void* d_out, int out_size, void* d_ws, size_t ws_size,
                              hipStream_t stream) {
    const float* X    = (const float*)d_in[0];
    const float* W    = (const float*)d_in[1];
    const int*   rows = (const int*)d_in[2];
    const int*   cols = (const int*)d_in[3];
    const float* vals = (const float*)d_in[4];
    float*       out  = (float*)d_out;

    const int M = in_sizes[0] / IN_FEAT;   // 100000
    const int E = in_sizes[2];             // 3200000

    unsigned short* S  = (unsigned short*)d_ws;               // M*128 bf16 = 25.6 MB
    unsigned short* Wt = S + (size_t)M * OUT_FEAT;            // 128*256 bf16 = 64 KB
    int* row_ptr = (int*)(Wt + IN_FEAT * OUT_FEAT);           // (M+1) ints

    prep_wt<<<(IN_FEAT * OUT_FEAT) / 256, 256, 0, stream>>>(W, Wt);
    rowptr_kernel<<<(M + 256) / 256 + 1, 256, 0, stream>>>(rows, row_ptr, E, M);
    gemm_bf16<<<(M + 127) / 128, 256, 0, stream>>>(X, Wt, S, M);
    spmm_bf16<<<(M + 3) / 4, 256, 0, stream>>>(cols, vals, S, row_ptr, out, M);
}

// Round 3
// 310.010 us; speedup vs baseline: 2.1053x; 1.0583x over previous
//
#include <hip/hip_runtime.h>

#define IN_FEAT 256
#define OUT_FEAT 128

typedef __attribute__((ext_vector_type(8))) short bf16x8;
typedef __attribute__((ext_vector_type(4))) float f32x4;

static __device__ __forceinline__ unsigned short f2bf(float f) {
    union { float f; unsigned u; } v; v.f = f;
    unsigned u = v.u;
    return (unsigned short)((u + 0x7FFFu + ((u >> 16) & 1u)) >> 16);
}
static __device__ __forceinline__ float bfl(unsigned u) {
    union { unsigned u; float f; } x; x.u = u << 16; return x.f;
}
static __device__ __forceinline__ float bfh(unsigned u) {
    union { unsigned u; float f; } x; x.u = u & 0xFFFF0000u; return x.f;
}

// ---- prep: Wt[n][k] = bf16(W[k][n]), Wt is [128][256] bf16 ----
__global__ __launch_bounds__(256) void prep_wt(const float* __restrict__ W,
                                               unsigned short* __restrict__ Wt) {
    int idx = blockIdx.x * 256 + threadIdx.x;      // 0..32767
    int n = idx >> 8, k = idx & 255;
    Wt[idx] = f2bf(W[(size_t)k * OUT_FEAT + n]);
}

// ---- prep: row_ptr[i] = lower_bound(rows, i), i in [0, N] ----
__global__ __launch_bounds__(256) void rowptr_kernel(const int* __restrict__ rows,
                                                     int* __restrict__ row_ptr,
                                                     int E, int N) {
    int i = blockIdx.x * 256 + threadIdx.x;
    if (i > N) return;
    int lo = 0, hi = E;
    while (lo < hi) {
        int mid = (lo + hi) >> 1;
        if (rows[mid] < i) lo = mid + 1; else hi = mid;
    }
    row_ptr[i] = lo;
}

// ---- GEMM v3: S = bf16(X @ W). Wt resident in LDS; A direct global->reg.
// Block 512 thr = 8 waves; wave w owns rows m0 + w*16 .. +16, all 128 cols.
// No per-K barriers: each wave free-runs K=256.
__global__ __launch_bounds__(512, 4) void gemm_v3(const float* __restrict__ X,
                                                  const unsigned short* __restrict__ Wt,
                                                  unsigned short* __restrict__ S, int M) {
    __shared__ unsigned short Bs[128 * 256];   // 64 KB, 16B-slot layout: (r<<5)|(s^(r&7))

    // stage Wt once: 4096 uint4 slots
    for (int i = threadIdx.x; i < 4096; i += 512) {
        int r = i >> 5, s = i & 31;
        ((uint4*)Bs)[(r << 5) | (s ^ (r & 7))] = ((const uint4*)Wt)[i];
    }
    __syncthreads();

    const int w = threadIdx.x >> 6;
    const int lane = threadIdx.x & 63;
    const int lr = lane & 15, lg = lane >> 4;
    const int m0 = blockIdx.x * 128;
    const int row = m0 + w * 16 + lr;
    const int crow = (row < M) ? row : (M - 1);
    const float4* xp = (const float4*)(X + (size_t)crow * IN_FEAT) + lg * 2;

    f32x4 acc[8];
#pragma unroll
    for (int ni = 0; ni < 8; ++ni) acc[ni] = (f32x4){0.f, 0.f, 0.f, 0.f};

#pragma unroll
    for (int kb = 0; kb < 8; ++kb) {           // k0 = kb*32, lane covers k0+lg*8..+8
        float4 f0 = xp[kb * 8];
        float4 f1 = xp[kb * 8 + 1];
        union { uint4 u; bf16x8 v; } a;
        a.u.x = (unsigned)f2bf(f0.x) | ((unsigned)f2bf(f0.y) << 16);
        a.u.y = (unsigned)f2bf(f0.z) | ((unsigned)f2bf(f0.w) << 16);
        a.u.z = (unsigned)f2bf(f1.x) | ((unsigned)f2bf(f1.y) << 16);
        a.u.w = (unsigned)f2bf(f1.z) | ((unsigned)f2bf(f1.w) << 16);
        const int sb = kb * 4 + lg;            // k-slot 0..31
#pragma unroll
        for (int ni = 0; ni < 8; ++ni) {
            int r2 = ni * 16 + lr;
            bf16x8 b = ((const bf16x8*)Bs)[(r2 << 5) | (sb ^ (r2 & 7))];
            acc[ni] = __builtin_amdgcn_mfma_f32_16x16x32_bf16(a.v, b, acc[ni], 0, 0, 0);
        }
    }

    // epilogue: acc -> LDS (reuse Bs) -> coalesced uint4 stores
    __syncthreads();
    unsigned short* Cs = Bs + w * 16 * 128;    // wave's 16x128 bf16 panel
#pragma unroll
    for (int ni = 0; ni < 8; ++ni)
#pragma unroll
        for (int j = 0; j < 4; ++j)
            Cs[(lg * 4 + j) * 128 + ni * 16 + lr] = f2bf(acc[ni][j]);
    __syncthreads();

    const int rows_blk = (M - m0 < 128) ? (M - m0) : 128;
    for (int i = threadIdx.x; i < 2048; i += 512) {
        int R = i >> 4;
        if (R < rows_blk)
            ((uint4*)(S + (size_t)(m0 + R) * OUT_FEAT))[i & 15] = ((const uint4*)Bs)[i];
    }
}

// ---- SpMM: out[r] = sum_e vals[e] * S[cols[e]]  (S bf16 [N][128]) ----
// 4 waves/block, one wave per row. lane: g=lane>>4 edge subgroup, fb=lane&15 feat block.
// 16 edges in flight per wave (4 uint4 gathers per lane).
__global__ __launch_bounds__(256) void spmm_bf16(const int* __restrict__ cols,
                                                 const float* __restrict__ vals,
                                                 const unsigned short* __restrict__ S,
                                                 const int* __restrict__ row_ptr,
                                                 float* __restrict__ out, int N) {
    const int w = threadIdx.x >> 6;
    const int lane = threadIdx.x & 63;
    const int r = blockIdx.x * 4 + w;
    if (r >= N) return;
    const int g = lane >> 4;
    const int fb = lane & 15;
    const int start = row_ptr[r], end = row_ptr[r + 1];

    float acc[8] = {0.f, 0.f, 0.f, 0.f, 0.f, 0.f, 0.f, 0.f};
    const unsigned short* Sb = S + fb * 8;

    for (int base = start; base < end; base += 16) {
        int   c[4]; float v[4]; uint4 p[4];
#pragma unroll
        for (int u = 0; u < 4; ++u) {
            int e = base + u * 4 + g;
            int ec = (e < end) ? e : (end - 1);
            c[u] = cols[ec];
            v[u] = (e < end) ? vals[ec] : 0.f;
        }
#pragma unroll
        for (int u = 0; u < 4; ++u)
            p[u] = *(const uint4*)(Sb + (size_t)c[u] * OUT_FEAT);
#pragma unroll
        for (int u = 0; u < 4; ++u) {
            float v0 = v[u];
            acc[0] += v0 * bfl(p[u].x); acc[1] += v0 * bfh(p[u].x);
            acc[2] += v0 * bfl(p[u].y); acc[3] += v0 * bfh(p[u].y);
            acc[4] += v0 * bfl(p[u].z); acc[5] += v0 * bfh(p[u].z);
            acc[6] += v0 * bfl(p[u].w); acc[7] += v0 * bfh(p[u].w);
        }
    }

#pragma unroll
    for (int j = 0; j < 8; ++j) {
        acc[j] += __shfl_xor(acc[j], 16);
        acc[j] += __shfl_xor(acc[j], 32);
    }
    if (g == 0) {
        *(float4*)(out + (size_t)r * OUT_FEAT + fb * 8) =
            make_float4(acc[0], acc[1], acc[2], acc[3]);
        *(float4*)(out + (size_t)r * OUT_FEAT + fb * 8 + 4) =
            make_float4(acc[4], acc[5], acc[6], acc[7]);
    }
}

extern "C" void kernel_launch(void* const* d_in, const int* in_sizes, int n_in,
                              void* d_out, int out_size, void* d_ws, size_t ws_size,
                              hipStream_t stream) {
    const float* X    = (const float*)d_in[0];
    const float* W    = (const float*)d_in[1];
    const int*   rows = (const int*)d_in[2];
    const int*   cols = (const int*)d_in[3];
    const float* vals = (const float*)d_in[4];
    float*       out  = (float*)d_out;

    const int M = in_sizes[0] / IN_FEAT;   // 100000
    const int E = in_sizes[2];             // 3200000

    unsigned short* S  = (unsigned short*)d_ws;               // M*128 bf16 = 25.6 MB
    unsigned short* Wt = S + (size_t)M * OUT_FEAT;            // 128*256 bf16 = 64 KB
    int* row_ptr = (int*)(Wt + IN_FEAT * OUT_FEAT);           // (M+1) ints

    prep_wt<<<(IN_FEAT * OUT_FEAT) / 256, 256, 0, stream>>>(W, Wt);
    rowptr_kernel<<<(M + 256) / 256 + 1, 256, 0, stream>>>(rows, row_ptr, E, M);
    gemm_v3<<<(M + 127) / 128, 512, 0, stream>>>(X, Wt, S, M);
    spmm_bf16<<<(M + 3) / 4, 256, 0, stream>>>(cols, vals, S, row_ptr, out, M);
}